// Round 5
// baseline (117.931 us; speedup 1.0000x reference)
//
#include <hip/hip_runtime.h>
#include <hip/hip_bf16.h>

#define B_  4
#define N_  512
#define D_  128
#define H_  8
#define DK  16
#define DFF 512
#define NB  32
#define KS  4            // key-split factor for attention

// ---------------- QKV projections: wave = 2 rows x 128 cols, z = Q/K/V ----------------
__global__ __launch_bounds__(256) void qkv_kernel(
    const float* __restrict__ A,
    const float* __restrict__ WQ, const float* __restrict__ WK, const float* __restrict__ WV,
    float* __restrict__ Qo, float* __restrict__ Ko, float* __restrict__ Vo)
{
    const float* Bw = blockIdx.z == 0 ? WQ : (blockIdx.z == 1 ? WK : WV);
    float*       C  = blockIdx.z == 0 ? Qo : (blockIdx.z == 1 ? Ko : Vo);
    const int lane = threadIdx.x & 63;
    const int rbase = __builtin_amdgcn_readfirstlane((blockIdx.x * 4 + (threadIdx.x >> 6)) * 2);
    const int col = lane * 2;

    float acc[2][2] = {};
#pragma unroll 4
    for (int k0 = 0; k0 < D_; k0 += 4) {
        float4 a0 = *(const float4*)&A[(size_t)(rbase + 0) * D_ + k0];
        float4 a1 = *(const float4*)&A[(size_t)(rbase + 1) * D_ + k0];
#pragma unroll
        for (int kk = 0; kk < 4; ++kk) {
            float2 bv = *(const float2*)&Bw[(size_t)(k0 + kk) * D_ + col];
            float x0 = (&a0.x)[kk], x1 = (&a1.x)[kk];
            acc[0][0] += x0 * bv.x; acc[0][1] += x0 * bv.y;
            acc[1][0] += x1 * bv.x; acc[1][1] += x1 * bv.y;
        }
    }
    *(float2*)&C[(size_t)(rbase + 0) * D_ + col] = make_float2(acc[0][0], acc[0][1]);
    *(float2*)&C[(size_t)(rbase + 1) * D_ + col] = make_float2(acc[1][0], acc[1][1]);
}

// ---------------- attention v4: QE fused in-block, key-split across blocks -------
__global__ __launch_bounds__(256) void attn4_kernel(
    const float* __restrict__ Q, const float* __restrict__ K, const float* __restrict__ V,
    const float* __restrict__ emb, const float* __restrict__ coords,
    float* __restrict__ P)
{
    const int tid  = threadIdx.x;
    const int wave = tid >> 6;
    const int lane = tid & 63;
    const int bid  = blockIdx.x;
    const int ks    = bid & (KS - 1);
    const int chunk = (bid >> 2) & 7;
    const int h     = (bid >> 5) & (H_ - 1);
    const int b     = bid >> 8;

    const int n   = chunk * 64 + lane;
    const int row = b * N_ + n;

    __shared__ float qel[64][NB + 1];
    __shared__ float ckrd[128][2];
    __shared__ float accl[4][64][17];

    // compute QE table in-block: thread (r = tid>>2) does 8 buckets
    {
        int r = tid >> 2, kp0 = (tid & 3) * 8;
        const float4* qg = (const float4*)(Q + (size_t)(b * N_ + chunk * 64 + r) * D_ + h * DK);
        float4 qa = qg[0], qb = qg[1], qc = qg[2], qd = qg[3];
#pragma unroll
        for (int j = 0; j < 8; ++j) {
            const float4* ep = (const float4*)(emb + (size_t)(kp0 + j) * D_ + h * DK);
            float4 e0 = ep[0], e1 = ep[1], e2 = ep[2], e3 = ep[3];
            float dot = qa.x*e0.x + qa.y*e0.y + qa.z*e0.z + qa.w*e0.w
                      + qb.x*e1.x + qb.y*e1.y + qb.z*e1.z + qb.w*e1.w
                      + qc.x*e2.x + qc.y*e2.y + qc.z*e2.z + qc.w*e2.w
                      + qd.x*e3.x + qd.y*e3.y + qd.z*e3.z + qd.w*e3.w;
            qel[r][kp0 + j] = dot;
        }
    }
    ((float*)ckrd)[tid] = coords[(size_t)(b * N_ + ks * 128) * 2 + tid];

    const float4* qp = (const float4*)(Q + (size_t)row * D_ + h * DK);
    const float4 q0 = qp[0], q1 = qp[1], q2 = qp[2], q3 = qp[3];
    const float cx = coords[(size_t)row * 2 + 0];
    const float cy = coords[(size_t)row * 2 + 1];

    __syncthreads();

    const size_t hdbase = (size_t)b * N_ * D_ + h * DK;

    float l = 0.f;
    float acc[16] = {};

    const int m0 = __builtin_amdgcn_readfirstlane(ks * 128 + wave * 32);
#pragma unroll 4
    for (int i = 0; i < 32; ++i) {
        const int m = m0 + i;
        const float4* kp = (const float4*)(K + hdbase + (size_t)m * D_);
        const float4 k0 = kp[0], k1 = kp[1], k2 = kp[2], k3 = kp[3];
        float dot = q0.x*k0.x + q0.y*k0.y + q0.z*k0.z + q0.w*k0.w
                  + q1.x*k1.x + q1.y*k1.y + q1.z*k1.z + q1.w*k1.w
                  + q2.x*k2.x + q2.y*k2.y + q2.z*k2.z + q2.w*k2.w
                  + q3.x*k3.x + q3.y*k3.y + q3.z*k3.z + q3.w*k3.w;
        const int mloc = m - ks * 128;
        float dx = cx - ckrd[mloc][0], dy = cy - ckrd[mloc][1];
        float dist = sqrtf(dx * dx + dy * dy);
        int bucket = (int)(dist * 32.0f);
        bucket = bucket > (NB - 1) ? (NB - 1) : bucket;
        float s = dot * 0.25f + qel[lane][bucket];
        float p = __expf(s);
        l += p;
        const float4* vp = (const float4*)(V + hdbase + (size_t)m * D_);
        const float4 v0 = vp[0], v1 = vp[1], v2 = vp[2], v3 = vp[3];
        acc[0]  += p * v0.x; acc[1]  += p * v0.y; acc[2]  += p * v0.z; acc[3]  += p * v0.w;
        acc[4]  += p * v1.x; acc[5]  += p * v1.y; acc[6]  += p * v1.z; acc[7]  += p * v1.w;
        acc[8]  += p * v2.x; acc[9]  += p * v2.y; acc[10] += p * v2.z; acc[11] += p * v2.w;
        acc[12] += p * v3.x; acc[13] += p * v3.y; acc[14] += p * v3.z; acc[15] += p * v3.w;
    }

    accl[wave][lane][16] = l;
#pragma unroll
    for (int j = 0; j < 16; ++j) accl[wave][lane][j] = acc[j];
    __syncthreads();

    float* pb = P + (size_t)bid * (64 * 17);
    for (int i = tid; i < 64 * 17; i += 256) {
        int r = i / 17, j = i - r * 17;
        pb[i] = accl[0][r][j] + accl[1][r][j] + accl[2][r][j] + accl[3][r][j];
    }
}

// ---------------- O-proj: combine KS partials in LDS, then wave = 1 row x 128 cols -----
__global__ __launch_bounds__(256) void oproj_kernel(
    const float* __restrict__ P, const float* __restrict__ WO,
    const float* __restrict__ hres, float* __restrict__ X1)
{
    const int tid = threadIdx.x;
    __shared__ float AOls[4][128];

    // combine: 4 rows x 128 cols
    for (int idx = tid; idx < 512; idx += 256) {
        int r = idx >> 7, d = idx & 127;
        int gr = blockIdx.x * 4 + r;
        int b = gr >> 9, n = gr & (N_ - 1);
        int chunk = n >> 6, rl = n & 63;
        int hh = d >> 4, dk = d & 15;
        size_t base = ((size_t)(((b * H_ + hh) * 8 + chunk) * KS)) * (64 * 17) + (size_t)rl * 17;
        float a = 0.f, l = 0.f;
#pragma unroll
        for (int s = 0; s < KS; ++s) {
            const float* ps = P + base + (size_t)s * (64 * 17);
            a += ps[dk];
            l += ps[16];
        }
        AOls[r][d] = a / l;
    }
    __syncthreads();

    const int lane = tid & 63;
    const int w = tid >> 6;
    const int gr = __builtin_amdgcn_readfirstlane(blockIdx.x * 4 + w);
    const int col = lane * 2;

    float acc0 = 0.f, acc1 = 0.f;
#pragma unroll 4
    for (int k0 = 0; k0 < D_; k0 += 4) {
        float4 a4 = *(const float4*)&AOls[w][k0];
#pragma unroll
        for (int kk = 0; kk < 4; ++kk) {
            float2 bv = *(const float2*)&WO[(size_t)(k0 + kk) * D_ + col];
            float a = (&a4.x)[kk];
            acc0 += a * bv.x; acc1 += a * bv.y;
        }
    }
    float2 rv = *(const float2*)&hres[(size_t)gr * D_ + col];
    *(float2*)&X1[(size_t)gr * D_ + col] = make_float2(acc0 + rv.x, acc1 + rv.y);
}

// ---------------- instance-norm stats -> affine tables T1 = r*g, T2 = be - m*r*g ------
__global__ __launch_bounds__(256) void stats_kernel(const float* __restrict__ X,
    const float* __restrict__ gamma, const float* __restrict__ beta,
    float* __restrict__ T1, float* __restrict__ T2)
{
    const int bb = blockIdx.x >> 5;
    const int dg = blockIdx.x & 31;
    const int dl = threadIdx.x & 3;
    const int nc = threadIdx.x >> 2;
    const float* xp = X + ((size_t)bb * N_ + nc * 8) * D_ + dg * 4 + dl;
    float s = 0.f, q = 0.f;
#pragma unroll
    for (int i = 0; i < 8; ++i) { float x = xp[(size_t)i * D_]; s += x; q += x * x; }
    __shared__ float rs[64][4], rq[64][4];
    rs[nc][dl] = s; rq[nc][dl] = q;
    __syncthreads();
    for (int off = 32; off >= 1; off >>= 1) {
        if (nc < off) { rs[nc][dl] += rs[nc + off][dl]; rq[nc][dl] += rq[nc + off][dl]; }
        __syncthreads();
    }
    if (threadIdx.x < 4) {
        int d = dg * 4 + threadIdx.x;
        float mean = rs[0][threadIdx.x] * (1.0f / N_);
        float var  = rq[0][threadIdx.x] * (1.0f / N_) - mean * mean;
        float r = 1.0f / sqrtf(var + 1e-5f);
        float t1 = r * gamma[d];
        T1[bb * D_ + d] = t1;
        T2[bb * D_ + d] = beta[d] - mean * t1;
    }
}

// ---------------- FFN1: A = norm(X1) built in LDS; wave = 2 rows x 128-col slice ------
__global__ __launch_bounds__(256) void ffn1_kernel(
    const float* __restrict__ X1, const float* __restrict__ T1, const float* __restrict__ T2,
    const float* __restrict__ w1, const float* __restrict__ b1, float* __restrict__ F1)
{
    const int tid = threadIdx.x;
    __shared__ float Als[8][128];
    {
        int idx = tid * 4;
        int r = idx >> 7, c = idx & 127;
        int gr = blockIdx.x * 8 + r;
        int b = gr >> 9;
        float4 x  = *(const float4*)&X1[(size_t)gr * D_ + c];
        float4 t1 = *(const float4*)&T1[b * D_ + c];
        float4 t2 = *(const float4*)&T2[b * D_ + c];
        float4 y;
        y.x = x.x * t1.x + t2.x; y.y = x.y * t1.y + t2.y;
        y.z = x.z * t1.z + t2.z; y.w = x.w * t1.w + t2.w;
        *(float4*)&Als[r][c] = y;
    }
    __syncthreads();

    const int lane = tid & 63;
    const int w = tid >> 6;
    const int rl = w * 2;
    const int gr = __builtin_amdgcn_readfirstlane(blockIdx.x * 8 + rl);
    const int col = blockIdx.y * 128 + lane * 2;

    float acc[2][2] = {};
#pragma unroll 4
    for (int k0 = 0; k0 < D_; k0 += 4) {
        float4 a0 = *(const float4*)&Als[rl + 0][k0];
        float4 a1 = *(const float4*)&Als[rl + 1][k0];
#pragma unroll
        for (int kk = 0; kk < 4; ++kk) {
            float2 bv = *(const float2*)&w1[(size_t)(k0 + kk) * DFF + col];
            float x0 = (&a0.x)[kk], x1 = (&a1.x)[kk];
            acc[0][0] += x0 * bv.x; acc[0][1] += x0 * bv.y;
            acc[1][0] += x1 * bv.x; acc[1][1] += x1 * bv.y;
        }
    }
    float2 bb = *(const float2*)&b1[col];
#pragma unroll
    for (int j = 0; j < 2; ++j) {
        float o0 = fmaxf(acc[j][0] + bb.x, 0.f);
        float o1 = fmaxf(acc[j][1] + bb.y, 0.f);
        *(float2*)&F1[(size_t)(gr + j) * DFF + col] = make_float2(o0, o1);
    }
}

// ---------------- FFN2: wave = 1 row x 128 cols, K=512; resid = norm(X1) fused --------
__global__ __launch_bounds__(256) void ffn2_kernel(
    const float* __restrict__ F1, const float* __restrict__ w2, const float* __restrict__ b2,
    const float* __restrict__ X1, const float* __restrict__ T1, const float* __restrict__ T2,
    float* __restrict__ X2)
{
    const int lane = threadIdx.x & 63;
    const int gr = __builtin_amdgcn_readfirstlane(blockIdx.x * 4 + (threadIdx.x >> 6));
    const int col = lane * 2;

    float acc0 = 0.f, acc1 = 0.f;
#pragma unroll 4
    for (int k0 = 0; k0 < DFF; k0 += 4) {
        float4 a4 = *(const float4*)&F1[(size_t)gr * DFF + k0];
#pragma unroll
        for (int kk = 0; kk < 4; ++kk) {
            float2 bv = *(const float2*)&w2[(size_t)(k0 + kk) * D_ + col];
            float a = (&a4.x)[kk];
            acc0 += a * bv.x; acc1 += a * bv.y;
        }
    }
    const int b = gr >> 9;
    float2 bb = *(const float2*)&b2[col];
    float2 x1 = *(const float2*)&X1[(size_t)gr * D_ + col];
    float2 t1 = *(const float2*)&T1[b * D_ + col];
    float2 t2 = *(const float2*)&T2[b * D_ + col];
    float o0 = acc0 + bb.x + (x1.x * t1.x + t2.x);
    float o1 = acc1 + bb.y + (x1.y * t1.y + t2.y);
    *(float2*)&X2[(size_t)gr * D_ + col] = make_float2(o0, o1);
}

// ---------------- final elementwise apply: out = X2*T1b + T2b ----------------
__global__ __launch_bounds__(256) void apply_kernel(const float* __restrict__ X,
    const float* __restrict__ T1, const float* __restrict__ T2, float* __restrict__ Y)
{
    int idx = (blockIdx.x * 256 + threadIdx.x) * 4;
    int d = idx & (D_ - 1);
    int b = idx >> 16;
    float4 x  = *(const float4*)&X[idx];
    float4 t1 = *(const float4*)&T1[b * D_ + d];
    float4 t2 = *(const float4*)&T2[b * D_ + d];
    float4 y;
    y.x = x.x * t1.x + t2.x; y.y = x.y * t1.y + t2.y;
    y.z = x.z * t1.z + t2.z; y.w = x.w * t1.w + t2.w;
    *(float4*)&Y[idx] = y;
}

extern "C" void kernel_launch(void* const* d_in, const int* in_sizes, int n_in,
                              void* d_out, int out_size, void* d_ws, size_t ws_size,
                              hipStream_t stream)
{
    const float* h      = (const float*)d_in[0];
    const float* coords = (const float*)d_in[1];
    const float* W_Q    = (const float*)d_in[2];
    const float* W_K    = (const float*)d_in[3];
    const float* W_V    = (const float*)d_in[4];
    const float* W_O    = (const float*)d_in[5];
    const float* emb    = (const float*)d_in[6];
    const float* w1     = (const float*)d_in[7];
    const float* b1     = (const float*)d_in[8];
    const float* w2     = (const float*)d_in[9];
    const float* b2     = (const float*)d_in[10];
    const float* g1     = (const float*)d_in[11];
    const float* be1    = (const float*)d_in[12];
    const float* g2     = (const float*)d_in[13];
    const float* be2    = (const float*)d_in[14];
    float* out = (float*)d_out;

    float* ws = (float*)d_ws;
    const size_t R = (size_t)B_ * N_;          // 2048 rows
    float* Qb  = ws;
    float* Kb  = Qb + R * D_;
    float* Vb  = Kb + R * D_;
    float* X1  = Vb + R * D_;
    float* F1  = X1 + R * D_;                  // R * DFF
    float* X2  = F1 + R * DFF;
    float* Pb  = X2 + R * D_;                  // 1024 * 64 * 17 partials
    float* T1a = Pb + (size_t)1024 * 64 * 17;
    float* T2a = T1a + B_ * D_;
    float* T1b = T2a + B_ * D_;
    float* T2b = T1b + B_ * D_;

    // 1. Q,K,V projections (768 blocks, 3/CU)
    qkv_kernel<<<dim3(256, 1, 3), 256, 0, stream>>>(h, W_Q, W_K, W_V, Qb, Kb, Vb);
    // 2. attention (QE fused; 1024 blocks, 4/CU) -> partials
    attn4_kernel<<<dim3(B_ * H_ * 8 * KS), 256, 0, stream>>>(Qb, Kb, Vb, emb, coords, Pb);
    // 3. O-projection (combine + residual fused; 512 blocks)
    oproj_kernel<<<dim3((int)R / 4), 256, 0, stream>>>(Pb, W_O, h, X1);
    // 4. instance-norm-1 stats -> affine tables
    stats_kernel<<<dim3(B_ * 32), 256, 0, stream>>>(X1, g1, be1, T1a, T2a);
    // 5. FFN1 (norm applied in LDS prologue; relu; 1024 blocks)
    ffn1_kernel<<<dim3(256, 4), 256, 0, stream>>>(X1, T1a, T2a, w1, b1, F1);
    // 6. FFN2 (+bias, + fused norm(X1) residual; 512 blocks)
    ffn2_kernel<<<dim3((int)R / 4), 256, 0, stream>>>(F1, w2, b2, X1, T1a, T2a, X2);
    // 7. instance-norm-2 stats
    stats_kernel<<<dim3(B_ * 32), 256, 0, stream>>>(X2, g2, be2, T1b, T2b);
    // 8. final apply -> out
    apply_kernel<<<dim3((int)(R * D_) / 1024), 256, 0, stream>>>(X2, T1b, T2b, out);
}

// Round 6
// 91.300 us; speedup vs baseline: 1.2917x; 1.2917x over previous
//
#include <hip/hip_runtime.h>
#include <hip/hip_bf16.h>

#define B_  4
#define N_  512
#define D_  128
#define H_  8
#define DK  16
#define DFF 512
#define NB  32
#define KS  8            // key-split factor for attention

// ---------------- GEMV-style skinny GEMM, parameterized rows/wave ----------------
// C = A[M,K] @ B[K,NT] (+bias) (+resid) (relu). Wave owns ROWS rows x 128-col slice
// (2 cols/lane, slice = blockIdx.y). A loads wave-uniform -> scalar; B coalesced.
// L2 B-traffic = (2048/ROWS) * 128 * K * 4B  -> keep ROWS high.
template <int NT, int K, int ROWS, int RELU>
__global__ __launch_bounds__(256) void gemv_kernel(
    const float* __restrict__ A,
    const float* __restrict__ B0, const float* __restrict__ B1, const float* __restrict__ B2,
    float* __restrict__ C0, float* __restrict__ C1, float* __restrict__ C2,
    const float* __restrict__ bias, const float* __restrict__ resid)
{
    const float* Bw = blockIdx.z == 0 ? B0 : (blockIdx.z == 1 ? B1 : B2);
    float*       C  = blockIdx.z == 0 ? C0 : (blockIdx.z == 1 ? C1 : C2);
    const int wave = threadIdx.x >> 6;
    const int lane = threadIdx.x & 63;
    const int rbase = __builtin_amdgcn_readfirstlane((blockIdx.x * 4 + wave) * ROWS);
    const int col = blockIdx.y * 128 + lane * 2;

    float acc[ROWS][2] = {};

#pragma unroll 2
    for (int k0 = 0; k0 < K; k0 += 4) {
        float4 a4[ROWS];
#pragma unroll
        for (int j = 0; j < ROWS; ++j)
            a4[j] = *(const float4*)&A[(size_t)(rbase + j) * K + k0];
#pragma unroll
        for (int kk = 0; kk < 4; ++kk) {
            float2 bv = *(const float2*)&Bw[(size_t)(k0 + kk) * NT + col];
#pragma unroll
            for (int j = 0; j < ROWS; ++j) {
                float a = (&a4[j].x)[kk];
                acc[j][0] += a * bv.x;
                acc[j][1] += a * bv.y;
            }
        }
    }

    float2 bb = make_float2(0.f, 0.f);
    if (bias) bb = *(const float2*)&bias[col];
#pragma unroll
    for (int j = 0; j < ROWS; ++j) {
        const int row = rbase + j;
        float o0 = acc[j][0] + bb.x;
        float o1 = acc[j][1] + bb.y;
        if (resid) {
            float2 rv = *(const float2*)&resid[(size_t)row * NT + col];
            o0 += rv.x; o1 += rv.y;
        }
        if (RELU) { o0 = fmaxf(o0, 0.f); o1 = fmaxf(o1, 0.f); }
        *(float2*)&C[(size_t)row * NT + col] = make_float2(o0, o1);
    }
}

// ---------------- QE precompute: QE[row,h,k] = Q[row,h,:] . emb[k,h,:] ----------------
__global__ __launch_bounds__(256) void qe_kernel(const float* __restrict__ Q,
                                                 const float* __restrict__ emb,
                                                 float* __restrict__ QE)
{
    int idx = blockIdx.x * 256 + threadIdx.x;   // [0, R*H*NB)
    int k   = idx & (NB - 1);
    int hh  = (idx >> 5) & (H_ - 1);
    int row = idx >> 8;
    const float4* qp = (const float4*)(Q + (size_t)row * D_ + hh * DK);
    const float4* ep = (const float4*)(emb + (size_t)k * D_ + hh * DK);
    float4 q0 = qp[0], q1 = qp[1], q2 = qp[2], q3 = qp[3];
    float4 e0 = ep[0], e1 = ep[1], e2 = ep[2], e3 = ep[3];
    float dot = q0.x*e0.x + q0.y*e0.y + q0.z*e0.z + q0.w*e0.w
              + q1.x*e1.x + q1.y*e1.y + q1.z*e1.z + q1.w*e1.w
              + q2.x*e2.x + q2.y*e2.y + q2.z*e2.z + q2.w*e2.w
              + q3.x*e3.x + q3.y*e3.y + q3.z*e3.z + q3.w*e3.w;
    QE[idx] = dot;
}

// ---------------- attention v5: lane-per-query-row, KS=8 key-split ----------------
// grid = B*H*8chunks*KS = 2048 blocks (26 KB LDS -> 6 blocks/CU, 24 waves/CU).
// Block (b,h,chunk,ks): 64 query rows (1/lane), keys [ks*64, ks*64+64); wave w
// covers 16 keys via wave-uniform scalar K/V loads. Partials -> P; combine later.
__global__ __launch_bounds__(256) void attn5_kernel(
    const float* __restrict__ Q, const float* __restrict__ K, const float* __restrict__ V,
    const float* __restrict__ QE, const float* __restrict__ coords,
    float* __restrict__ P)
{
    const int tid  = threadIdx.x;
    const int wave = tid >> 6;
    const int lane = tid & 63;
    const int bid  = blockIdx.x;
    const int ks    = bid & 7;
    const int chunk = (bid >> 3) & 7;
    const int h     = (bid >> 6) & (H_ - 1);
    const int b     = bid >> 9;

    const int n   = chunk * 64 + lane;
    const int row = b * N_ + n;

    __shared__ float qel[64][NB + 1];
    __shared__ float ckrd[64][2];
    __shared__ float accl[4][64][17];

    {   // stage QE table: 64 rows x 32 buckets
        int r = tid >> 2, part = tid & 3;
        const float* src = QE + ((size_t)(b * N_ + chunk * 64 + r) * H_ + h) * NB + part * 8;
#pragma unroll
        for (int j = 0; j < 8; ++j) qel[r][part * 8 + j] = src[j];
    }
    if (tid < 128)
        ((float*)ckrd)[tid] = coords[(size_t)(b * N_ + ks * 64) * 2 + tid];

    const float4* qp = (const float4*)(Q + (size_t)row * D_ + h * DK);
    const float4 q0 = qp[0], q1 = qp[1], q2 = qp[2], q3 = qp[3];
    const float cx = coords[(size_t)row * 2 + 0];
    const float cy = coords[(size_t)row * 2 + 1];

    __syncthreads();

    const size_t hdbase = (size_t)b * N_ * D_ + h * DK;

    float l = 0.f;
    float acc[16] = {};

    const int m0 = __builtin_amdgcn_readfirstlane(ks * 64 + wave * 16);
#pragma unroll 4
    for (int i = 0; i < 16; ++i) {
        const int m = m0 + i;
        const float4* kp = (const float4*)(K + hdbase + (size_t)m * D_);
        const float4 k0 = kp[0], k1 = kp[1], k2 = kp[2], k3 = kp[3];
        float dot = q0.x*k0.x + q0.y*k0.y + q0.z*k0.z + q0.w*k0.w
                  + q1.x*k1.x + q1.y*k1.y + q1.z*k1.z + q1.w*k1.w
                  + q2.x*k2.x + q2.y*k2.y + q2.z*k2.z + q2.w*k2.w
                  + q3.x*k3.x + q3.y*k3.y + q3.z*k3.z + q3.w*k3.w;
        const int mloc = m - ks * 64;
        float dx = cx - ckrd[mloc][0], dy = cy - ckrd[mloc][1];
        float dist = sqrtf(dx * dx + dy * dy);
        int bucket = (int)(dist * 32.0f);
        bucket = bucket > (NB - 1) ? (NB - 1) : bucket;
        float s = dot * 0.25f + qel[lane][bucket];
        float p = __expf(s);
        l += p;
        const float4* vp = (const float4*)(V + hdbase + (size_t)m * D_);
        const float4 v0 = vp[0], v1 = vp[1], v2 = vp[2], v3 = vp[3];
        acc[0]  += p * v0.x; acc[1]  += p * v0.y; acc[2]  += p * v0.z; acc[3]  += p * v0.w;
        acc[4]  += p * v1.x; acc[5]  += p * v1.y; acc[6]  += p * v1.z; acc[7]  += p * v1.w;
        acc[8]  += p * v2.x; acc[9]  += p * v2.y; acc[10] += p * v2.z; acc[11] += p * v2.w;
        acc[12] += p * v3.x; acc[13] += p * v3.y; acc[14] += p * v3.z; acc[15] += p * v3.w;
    }

    accl[wave][lane][16] = l;
#pragma unroll
    for (int j = 0; j < 16; ++j) accl[wave][lane][j] = acc[j];
    __syncthreads();

    float* pb = P + (size_t)bid * (64 * 17);
    for (int i = tid; i < 64 * 17; i += 256) {
        int r = i / 17, j = i - r * 17;
        pb[i] = accl[0][r][j] + accl[1][r][j] + accl[2][r][j] + accl[3][r][j];
    }
}

// combine KS partial slices -> normalized attention output AO[row][h*16+dk]
__global__ __launch_bounds__(256) void attn_combine_kernel(
    const float* __restrict__ P, float* __restrict__ AO)
{
    int idx = blockIdx.x * 256 + threadIdx.x;   // [0, R*D)
    int d  = idx & (D_ - 1);
    int r  = idx >> 7;
    int h  = d >> 4, dk = d & 15;
    int b  = r >> 9, n = r & (N_ - 1);
    int chunk = n >> 6, rl = n & 63;
    size_t base = ((size_t)(((b * H_ + h) * 8 + chunk) * KS)) * (64 * 17) + (size_t)rl * 17;
    float a = 0.f, l = 0.f;
#pragma unroll
    for (int s = 0; s < KS; ++s) {
        const float* ps = P + base + (size_t)s * (64 * 17);
        a += ps[dk];
        l += ps[16];
    }
    AO[idx] = a / l;
}

// ---------------- instance-norm stats -> affine tables T1 = r*g, T2 = be - m*r*g ------
__global__ __launch_bounds__(256) void stats_kernel(const float* __restrict__ X,
    const float* __restrict__ gamma, const float* __restrict__ beta,
    float* __restrict__ T1, float* __restrict__ T2)
{
    // grid = B*8; block handles (b, group of 16 d's); 16 n-chunks of 32
    const int b  = blockIdx.x >> 3;
    const int dg = blockIdx.x & 7;
    const int dl = threadIdx.x & 15;
    const int nc = threadIdx.x >> 4;
    const int d  = dg * 16 + dl;
    const float* xb = X + (size_t)b * N_ * D_ + d;
    float s = 0.f, q = 0.f;
    for (int i = 0; i < 32; ++i) {
        float x = xb[(size_t)(nc * 32 + i) * D_];
        s += x; q += x * x;
    }
    __shared__ float ls[16][17], lq[16][17];
    ls[nc][dl] = s; lq[nc][dl] = q;
    __syncthreads();
    if (threadIdx.x < 16) {
        float S = 0.f, Q2 = 0.f;
#pragma unroll
        for (int i = 0; i < 16; ++i) { S += ls[i][threadIdx.x]; Q2 += lq[i][threadIdx.x]; }
        int dd = dg * 16 + threadIdx.x;
        float mean = S * (1.0f / N_);
        float var  = Q2 * (1.0f / N_) - mean * mean;
        float r = 1.0f / sqrtf(var + 1e-5f);
        float t1 = r * gamma[dd];
        T1[b * D_ + dd] = t1;
        T2[b * D_ + dd] = beta[dd] - mean * t1;
    }
}

// ---------------- elementwise apply: Y = X*T1 + T2 ----------------
__global__ __launch_bounds__(256) void apply_kernel(const float* __restrict__ X,
    const float* __restrict__ T1, const float* __restrict__ T2, float* __restrict__ Y)
{
    int idx = (blockIdx.x * 256 + threadIdx.x) * 4;
    int d = idx & (D_ - 1);
    int b = idx >> 16;
    float4 x  = *(const float4*)&X[idx];
    float4 t1 = *(const float4*)&T1[b * D_ + d];
    float4 t2 = *(const float4*)&T2[b * D_ + d];
    float4 y;
    y.x = x.x * t1.x + t2.x; y.y = x.y * t1.y + t2.y;
    y.z = x.z * t1.z + t2.z; y.w = x.w * t1.w + t2.w;
    *(float4*)&Y[idx] = y;
}

// ---------------- FFN2 split-K: partial C_s = F1[:, s*128:(s+1)*128] @ w2-slice -------
__global__ __launch_bounds__(256) void ffn2s_kernel(
    const float* __restrict__ F1, const float* __restrict__ w2, float* __restrict__ Pf)
{
    const int wave = threadIdx.x >> 6;
    const int lane = threadIdx.x & 63;
    const int rbase = __builtin_amdgcn_readfirstlane((blockIdx.x * 4 + wave) * 8);
    const int col = lane * 2;
    const int s = blockIdx.z;
    const int kbeg = s * 128;

    float acc[8][2] = {};
#pragma unroll 2
    for (int k0 = kbeg; k0 < kbeg + 128; k0 += 4) {
        float4 a4[8];
#pragma unroll
        for (int j = 0; j < 8; ++j)
            a4[j] = *(const float4*)&F1[(size_t)(rbase + j) * DFF + k0];
#pragma unroll
        for (int kk = 0; kk < 4; ++kk) {
            float2 bv = *(const float2*)&w2[(size_t)(k0 + kk) * D_ + col];
#pragma unroll
            for (int j = 0; j < 8; ++j) {
                float a = (&a4[j].x)[kk];
                acc[j][0] += a * bv.x;
                acc[j][1] += a * bv.y;
            }
        }
    }
#pragma unroll
    for (int j = 0; j < 8; ++j)
        *(float2*)&Pf[((size_t)s * (B_ * N_) + rbase + j) * D_ + col] =
            make_float2(acc[j][0], acc[j][1]);
}

// ---------------- FFN2 combine: X2 = sum_s Pf[s] + b2 + H1 (residual) ----------------
__global__ __launch_bounds__(256) void fcomb_kernel(
    const float* __restrict__ Pf, const float* __restrict__ b2,
    const float* __restrict__ H1, float* __restrict__ X2)
{
    int idx = (blockIdx.x * 256 + threadIdx.x) * 4;
    int d = idx & (D_ - 1);
    float4 o = *(const float4*)&b2[d];
    float4 r = *(const float4*)&H1[idx];
    o.x += r.x; o.y += r.y; o.z += r.z; o.w += r.w;
#pragma unroll
    for (int s = 0; s < 4; ++s) {
        float4 p = *(const float4*)&Pf[(size_t)s * (B_ * N_ * D_) + idx];
        o.x += p.x; o.y += p.y; o.z += p.z; o.w += p.w;
    }
    *(float4*)&X2[idx] = o;
}

extern "C" void kernel_launch(void* const* d_in, const int* in_sizes, int n_in,
                              void* d_out, int out_size, void* d_ws, size_t ws_size,
                              hipStream_t stream)
{
    const float* h      = (const float*)d_in[0];
    const float* coords = (const float*)d_in[1];
    const float* W_Q    = (const float*)d_in[2];
    const float* W_K    = (const float*)d_in[3];
    const float* W_V    = (const float*)d_in[4];
    const float* W_O    = (const float*)d_in[5];
    const float* emb    = (const float*)d_in[6];
    const float* w1     = (const float*)d_in[7];
    const float* b1     = (const float*)d_in[8];
    const float* w2     = (const float*)d_in[9];
    const float* b2     = (const float*)d_in[10];
    const float* g1     = (const float*)d_in[11];
    const float* be1    = (const float*)d_in[12];
    const float* g2     = (const float*)d_in[13];
    const float* be2    = (const float*)d_in[14];
    float* out = (float*)d_out;

    float* ws = (float*)d_ws;
    const size_t R = (size_t)B_ * N_;          // 2048 rows
    float* Qb  = ws;
    float* Kb  = Qb + R * D_;
    float* Vb  = Kb + R * D_;
    float* QEb = Vb + R * D_;                  // R*H*NB = 512K
    float* AO  = QEb + R * H_ * NB;
    float* X1  = AO + R * D_;
    float* H1  = X1 + R * D_;
    float* F1  = H1 + R * D_;                  // R * DFF
    float* X2  = F1 + R * DFF;
    float* Pb  = X2 + R * D_;                  // 2048 * 64 * 17
    float* Pf  = Pb + (size_t)2048 * 64 * 17;  // 4 * R * D
    float* T1a = Pf + (size_t)4 * R * D_;
    float* T2a = T1a + B_ * D_;
    float* T1b = T2a + B_ * D_;
    float* T2b = T1b + B_ * D_;

    // 1. Q,K,V projections (ROWS=4; 128x3 blocks; low weight re-streaming)
    gemv_kernel<128, 128, 4, 0><<<dim3(128, 1, 3), 256, 0, stream>>>(
        h, W_Q, W_K, W_V, Qb, Kb, Vb, nullptr, nullptr);
    // 2. QE table
    qe_kernel<<<dim3(2048), 256, 0, stream>>>(Qb, emb, QEb);
    // 3. attention (KS=8 -> 2048 blocks) + combine
    attn5_kernel<<<dim3(2048), 256, 0, stream>>>(Qb, Kb, Vb, QEb, coords, Pb);
    attn_combine_kernel<<<dim3((int)(R * D_) / 256), 256, 0, stream>>>(Pb, AO);
    // 4. O-projection + residual h
    gemv_kernel<128, 128, 4, 0><<<dim3(128, 1, 1), 256, 0, stream>>>(
        AO, W_O, W_O, W_O, X1, X1, X1, nullptr, h);
    // 5. instance-norm-1 stats + apply -> H1
    stats_kernel<<<dim3(B_ * 8), 256, 0, stream>>>(X1, g1, be1, T1a, T2a);
    apply_kernel<<<dim3((int)(R * D_) / 1024), 256, 0, stream>>>(X1, T1a, T2a, H1);
    // 6. FFN1 (ROWS=8, 4 col-slices; relu)
    gemv_kernel<512, 128, 8, 1><<<dim3(64, 4, 1), 256, 0, stream>>>(
        H1, w1, w1, w1, F1, F1, F1, b1, nullptr);
    // 7. FFN2 split-K partials + combine (+bias, +H1 residual)
    ffn2s_kernel<<<dim3(64, 1, 4), 256, 0, stream>>>(F1, w2, Pf);
    fcomb_kernel<<<dim3((int)(R * D_) / 1024), 256, 0, stream>>>(Pf, b2, H1, X2);
    // 8. instance-norm-2 stats + apply -> out
    stats_kernel<<<dim3(B_ * 8), 256, 0, stream>>>(X2, g2, be2, T1b, T2b);
    apply_kernel<<<dim3((int)(R * D_) / 1024), 256, 0, stream>>>(X2, T1b, T2b, out);
}

// Round 7
// 86.618 us; speedup vs baseline: 1.3615x; 1.0541x over previous
//
#include <hip/hip_runtime.h>
#include <hip/hip_bf16.h>

#define B_  4
#define N_  512
#define D_  128
#define H_  8
#define DK  16
#define DFF 512
#define NB  32
#define KS  8            // key-split factor for attention
#define FS  8            // ffn2 K-split factor

// ---------------- QKV projections + fused QE table ----------------
// Wave = 4 rows x 128 cols (2/lane); block = 16 rows. z selects Q/K/V weight.
// z==0 blocks additionally compute QE[row,h,k] = Q[row,h,:].emb[k,h,:] from the
// freshly computed Q rows staged in LDS (emb is 16KB -> L1-resident).
__global__ __launch_bounds__(256) void qkv_qe_kernel(
    const float* __restrict__ A,
    const float* __restrict__ WQ, const float* __restrict__ WK, const float* __restrict__ WV,
    const float* __restrict__ emb,
    float* __restrict__ Qo, float* __restrict__ Ko, float* __restrict__ Vo,
    float* __restrict__ QE)
{
    const float* Bw = blockIdx.z == 0 ? WQ : (blockIdx.z == 1 ? WK : WV);
    float*       C  = blockIdx.z == 0 ? Qo : (blockIdx.z == 1 ? Ko : Vo);
    const int wave = threadIdx.x >> 6;
    const int lane = threadIdx.x & 63;
    const int rbase = __builtin_amdgcn_readfirstlane((blockIdx.x * 4 + wave) * 4);
    const int col = lane * 2;

    float acc[4][2] = {};
#pragma unroll 2
    for (int k0 = 0; k0 < D_; k0 += 4) {
        float4 a4[4];
#pragma unroll
        for (int j = 0; j < 4; ++j)
            a4[j] = *(const float4*)&A[(size_t)(rbase + j) * D_ + k0];
#pragma unroll
        for (int kk = 0; kk < 4; ++kk) {
            float2 bv = *(const float2*)&Bw[(size_t)(k0 + kk) * D_ + col];
#pragma unroll
            for (int j = 0; j < 4; ++j) {
                float a = (&a4[j].x)[kk];
                acc[j][0] += a * bv.x;
                acc[j][1] += a * bv.y;
            }
        }
    }
#pragma unroll
    for (int j = 0; j < 4; ++j)
        *(float2*)&C[(size_t)(rbase + j) * D_ + col] = make_float2(acc[j][0], acc[j][1]);

    if (blockIdx.z == 0) {
        __shared__ float Qls[16][132];
#pragma unroll
        for (int j = 0; j < 4; ++j)
            *(float2*)&Qls[wave * 4 + j][col] = make_float2(acc[j][0], acc[j][1]);
        __syncthreads();
        // thread -> (row r of 16, head h of 8, k-half of 2), 16 buckets each
        const int r  = threadIdx.x >> 4;
        const int hh = (threadIdx.x & 15) >> 1;
        const int k0 = (threadIdx.x & 1) * 16;
        const int grow = blockIdx.x * 16 + r;
        const float4* qv = (const float4*)&Qls[r][hh * DK];
        const float4 qa = qv[0], qb = qv[1], qc = qv[2], qd = qv[3];
        float* qe_out = QE + ((size_t)grow * H_ + hh) * NB + k0;
#pragma unroll 4
        for (int k = 0; k < 16; ++k) {
            const float4* ep = (const float4*)(emb + (size_t)(k0 + k) * D_ + hh * DK);
            float4 e0 = ep[0], e1 = ep[1], e2 = ep[2], e3 = ep[3];
            float dot = qa.x*e0.x + qa.y*e0.y + qa.z*e0.z + qa.w*e0.w
                      + qb.x*e1.x + qb.y*e1.y + qb.z*e1.z + qb.w*e1.w
                      + qc.x*e2.x + qc.y*e2.y + qc.z*e2.z + qc.w*e2.w
                      + qd.x*e3.x + qd.y*e3.y + qd.z*e3.z + qd.w*e3.w;
            qe_out[k] = dot;
        }
    }
}

// ---------------- attention: lane-per-query-row, KS=8 key-split ----------------
__global__ __launch_bounds__(256) void attn5_kernel(
    const float* __restrict__ Q, const float* __restrict__ K, const float* __restrict__ V,
    const float* __restrict__ QE, const float* __restrict__ coords,
    float* __restrict__ P)
{
    const int tid  = threadIdx.x;
    const int wave = tid >> 6;
    const int lane = tid & 63;
    const int bid  = blockIdx.x;
    const int ks    = bid & 7;
    const int chunk = (bid >> 3) & 7;
    const int h     = (bid >> 6) & (H_ - 1);
    const int b     = bid >> 9;

    const int n   = chunk * 64 + lane;
    const int row = b * N_ + n;

    __shared__ float qel[64][NB + 1];
    __shared__ float ckrd[64][2];
    __shared__ float accl[4][64][17];

    {   // stage QE table: 64 rows x 32 buckets
        int r = tid >> 2, part = tid & 3;
        const float* src = QE + ((size_t)(b * N_ + chunk * 64 + r) * H_ + h) * NB + part * 8;
#pragma unroll
        for (int j = 0; j < 8; ++j) qel[r][part * 8 + j] = src[j];
    }
    if (tid < 128)
        ((float*)ckrd)[tid] = coords[(size_t)(b * N_ + ks * 64) * 2 + tid];

    const float4* qp = (const float4*)(Q + (size_t)row * D_ + h * DK);
    const float4 q0 = qp[0], q1 = qp[1], q2 = qp[2], q3 = qp[3];
    const float cx = coords[(size_t)row * 2 + 0];
    const float cy = coords[(size_t)row * 2 + 1];

    __syncthreads();

    const size_t hdbase = (size_t)b * N_ * D_ + h * DK;

    float l = 0.f;
    float acc[16] = {};

    const int m0 = __builtin_amdgcn_readfirstlane(ks * 64 + wave * 16);
#pragma unroll 4
    for (int i = 0; i < 16; ++i) {
        const int m = m0 + i;
        const float4* kp = (const float4*)(K + hdbase + (size_t)m * D_);
        const float4 k0 = kp[0], k1 = kp[1], k2 = kp[2], k3 = kp[3];
        float dot = q0.x*k0.x + q0.y*k0.y + q0.z*k0.z + q0.w*k0.w
                  + q1.x*k1.x + q1.y*k1.y + q1.z*k1.z + q1.w*k1.w
                  + q2.x*k2.x + q2.y*k2.y + q2.z*k2.z + q2.w*k2.w
                  + q3.x*k3.x + q3.y*k3.y + q3.z*k3.z + q3.w*k3.w;
        const int mloc = m - ks * 64;
        float dx = cx - ckrd[mloc][0], dy = cy - ckrd[mloc][1];
        float dist = sqrtf(dx * dx + dy * dy);
        int bucket = (int)(dist * 32.0f);
        bucket = bucket > (NB - 1) ? (NB - 1) : bucket;
        float s = dot * 0.25f + qel[lane][bucket];
        float p = __expf(s);
        l += p;
        const float4* vp = (const float4*)(V + hdbase + (size_t)m * D_);
        const float4 v0 = vp[0], v1 = vp[1], v2 = vp[2], v3 = vp[3];
        acc[0]  += p * v0.x; acc[1]  += p * v0.y; acc[2]  += p * v0.z; acc[3]  += p * v0.w;
        acc[4]  += p * v1.x; acc[5]  += p * v1.y; acc[6]  += p * v1.z; acc[7]  += p * v1.w;
        acc[8]  += p * v2.x; acc[9]  += p * v2.y; acc[10] += p * v2.z; acc[11] += p * v2.w;
        acc[12] += p * v3.x; acc[13] += p * v3.y; acc[14] += p * v3.z; acc[15] += p * v3.w;
    }

    accl[wave][lane][16] = l;
#pragma unroll
    for (int j = 0; j < 16; ++j) accl[wave][lane][j] = acc[j];
    __syncthreads();

    float* pb = P + (size_t)bid * (64 * 17);
    for (int i = tid; i < 64 * 17; i += 256) {
        int r = i / 17, j = i - r * 17;
        pb[i] = accl[0][r][j] + accl[1][r][j] + accl[2][r][j] + accl[3][r][j];
    }
}

// ---------------- O-proj: combine KS partials in LDS + ROWS=4 GEMV + h residual ------
__global__ __launch_bounds__(256) void oproj_kernel(
    const float* __restrict__ P, const float* __restrict__ WO,
    const float* __restrict__ hres, float* __restrict__ X1)
{
    const int tid = threadIdx.x;
    const int gr0 = blockIdx.x * 16;
    __shared__ float AOls[16][128];
    __shared__ float lsl[16][8];

    // softmax denominators: 128 (row, head) pairs
    if (tid < 128) {
        int r = tid >> 3, hh = tid & 7;
        int gr = gr0 + r;
        int b = gr >> 9, n = gr & (N_ - 1);
        int chunk = n >> 6, rl = n & 63;
        size_t base = ((size_t)(((b * H_ + hh) * 8 + chunk) * KS)) * (64 * 17) + (size_t)rl * 17;
        float l = 0.f;
#pragma unroll
        for (int s = 0; s < KS; ++s) l += P[base + (size_t)s * (64 * 17) + 16];
        lsl[r][hh] = l;
    }

    // numerators: 16 rows x 128 d = 2048, 8 per thread
    float asum[8];
#pragma unroll
    for (int j = 0; j < 8; ++j) {
        int i = tid + j * 256;
        int r = i >> 7, d = i & 127;
        int gr = gr0 + r;
        int b = gr >> 9, n = gr & (N_ - 1);
        int chunk = n >> 6, rl = n & 63;
        int hh = d >> 4, dk = d & 15;
        size_t base = ((size_t)(((b * H_ + hh) * 8 + chunk) * KS)) * (64 * 17) + (size_t)rl * 17 + dk;
        float a = 0.f;
#pragma unroll
        for (int s = 0; s < KS; ++s) a += P[base + (size_t)s * (64 * 17)];
        asum[j] = a;
    }
    __syncthreads();
#pragma unroll
    for (int j = 0; j < 8; ++j) {
        int i = tid + j * 256;
        int r = i >> 7, d = i & 127;
        AOls[r][d] = asum[j] / lsl[r][d >> 4];
    }
    __syncthreads();

    const int wave = tid >> 6;
    const int lane = tid & 63;
    const int rl = wave * 4;
    const int grb = __builtin_amdgcn_readfirstlane(gr0 + rl);
    const int col = lane * 2;

    float acc[4][2] = {};
#pragma unroll 2
    for (int k0 = 0; k0 < D_; k0 += 4) {
        float4 a4[4];
#pragma unroll
        for (int j = 0; j < 4; ++j) a4[j] = *(const float4*)&AOls[rl + j][k0];
#pragma unroll
        for (int kk = 0; kk < 4; ++kk) {
            float2 bv = *(const float2*)&WO[(size_t)(k0 + kk) * D_ + col];
#pragma unroll
            for (int j = 0; j < 4; ++j) {
                float a = (&a4[j].x)[kk];
                acc[j][0] += a * bv.x;
                acc[j][1] += a * bv.y;
            }
        }
    }
#pragma unroll
    for (int j = 0; j < 4; ++j) {
        float2 rv = *(const float2*)&hres[(size_t)(grb + j) * D_ + col];
        *(float2*)&X1[(size_t)(grb + j) * D_ + col] =
            make_float2(acc[j][0] + rv.x, acc[j][1] + rv.y);
    }
}

// ---------------- instance-norm stats -> affine tables T1 = r*g, T2 = be - m*r*g ------
__global__ __launch_bounds__(256) void stats_kernel(const float* __restrict__ X,
    const float* __restrict__ gamma, const float* __restrict__ beta,
    float* __restrict__ T1, float* __restrict__ T2)
{
    const int b  = blockIdx.x >> 3;
    const int dg = blockIdx.x & 7;
    const int dl = threadIdx.x & 15;
    const int nc = threadIdx.x >> 4;
    const int d  = dg * 16 + dl;
    const float* xb = X + (size_t)b * N_ * D_ + d;
    float s = 0.f, q = 0.f;
    for (int i = 0; i < 32; ++i) {
        float x = xb[(size_t)(nc * 32 + i) * D_];
        s += x; q += x * x;
    }
    __shared__ float ls[16][17], lq[16][17];
    ls[nc][dl] = s; lq[nc][dl] = q;
    __syncthreads();
    if (threadIdx.x < 16) {
        float S = 0.f, Q2 = 0.f;
#pragma unroll
        for (int i = 0; i < 16; ++i) { S += ls[i][threadIdx.x]; Q2 += lq[i][threadIdx.x]; }
        int dd = dg * 16 + threadIdx.x;
        float mean = S * (1.0f / N_);
        float var  = Q2 * (1.0f / N_) - mean * mean;
        float r = 1.0f / sqrtf(var + 1e-5f);
        float t1 = r * gamma[dd];
        T1[b * D_ + dd] = t1;
        T2[b * D_ + dd] = beta[dd] - mean * t1;
    }
}

// ---------------- FFN1: norm(X1) prologue in LDS; wave = 8 rows x 128-col slice ------
__global__ __launch_bounds__(256) void ffn1_kernel(
    const float* __restrict__ X1, const float* __restrict__ T1, const float* __restrict__ T2,
    const float* __restrict__ w1, const float* __restrict__ b1, float* __restrict__ F1)
{
    __shared__ float Als[32][128];
    const int gr0 = blockIdx.x * 32;
    const int b = gr0 >> 9;
    for (int i = threadIdx.x * 4; i < 32 * 128; i += 1024) {
        int r = i >> 7, c = i & 127;
        float4 x  = *(const float4*)&X1[(size_t)(gr0 + r) * D_ + c];
        float4 t1 = *(const float4*)&T1[b * D_ + c];
        float4 t2 = *(const float4*)&T2[b * D_ + c];
        float4 y;
        y.x = x.x * t1.x + t2.x; y.y = x.y * t1.y + t2.y;
        y.z = x.z * t1.z + t2.z; y.w = x.w * t1.w + t2.w;
        *(float4*)&Als[r][c] = y;
    }
    __syncthreads();

    const int wave = threadIdx.x >> 6;
    const int lane = threadIdx.x & 63;
    const int rl = wave * 8;
    const int grb = __builtin_amdgcn_readfirstlane(gr0 + rl);
    const int col = blockIdx.y * 128 + lane * 2;

    float acc[8][2] = {};
#pragma unroll 2
    for (int k0 = 0; k0 < D_; k0 += 4) {
        float4 a4[8];
#pragma unroll
        for (int j = 0; j < 8; ++j) a4[j] = *(const float4*)&Als[rl + j][k0];
#pragma unroll
        for (int kk = 0; kk < 4; ++kk) {
            float2 bv = *(const float2*)&w1[(size_t)(k0 + kk) * DFF + col];
#pragma unroll
            for (int j = 0; j < 8; ++j) {
                float a = (&a4[j].x)[kk];
                acc[j][0] += a * bv.x;
                acc[j][1] += a * bv.y;
            }
        }
    }
    float2 bb = *(const float2*)&b1[col];
#pragma unroll
    for (int j = 0; j < 8; ++j) {
        float o0 = fmaxf(acc[j][0] + bb.x, 0.f);
        float o1 = fmaxf(acc[j][1] + bb.y, 0.f);
        *(float2*)&F1[(size_t)(grb + j) * DFF + col] = make_float2(o0, o1);
    }
}

// ---------------- FFN2 split-K (FS=8): partial C_s -----------------------------------
__global__ __launch_bounds__(256) void ffn2s_kernel(
    const float* __restrict__ F1, const float* __restrict__ w2, float* __restrict__ Pf)
{
    const int wave = threadIdx.x >> 6;
    const int lane = threadIdx.x & 63;
    const int rbase = __builtin_amdgcn_readfirstlane((blockIdx.x * 4 + wave) * 8);
    const int col = lane * 2;
    const int s = blockIdx.z;
    const int kbeg = s * (DFF / FS);

    float acc[8][2] = {};
#pragma unroll 2
    for (int k0 = kbeg; k0 < kbeg + DFF / FS; k0 += 4) {
        float4 a4[8];
#pragma unroll
        for (int j = 0; j < 8; ++j)
            a4[j] = *(const float4*)&F1[(size_t)(rbase + j) * DFF + k0];
#pragma unroll
        for (int kk = 0; kk < 4; ++kk) {
            float2 bv = *(const float2*)&w2[(size_t)(k0 + kk) * D_ + col];
#pragma unroll
            for (int j = 0; j < 8; ++j) {
                float a = (&a4[j].x)[kk];
                acc[j][0] += a * bv.x;
                acc[j][1] += a * bv.y;
            }
        }
    }
#pragma unroll
    for (int j = 0; j < 8; ++j)
        *(float2*)&Pf[((size_t)s * (B_ * N_) + rbase + j) * D_ + col] =
            make_float2(acc[j][0], acc[j][1]);
}

// ---------------- FFN2 combine: X2 = sum_s Pf[s] + b2 + (X1*T1+T2) residual ----------
__global__ __launch_bounds__(256) void fcomb_kernel(
    const float* __restrict__ Pf, const float* __restrict__ b2,
    const float* __restrict__ X1, const float* __restrict__ T1, const float* __restrict__ T2,
    float* __restrict__ X2)
{
    int idx = (blockIdx.x * 256 + threadIdx.x) * 4;
    int d = idx & (D_ - 1);
    int b = idx >> 16;
    float4 o  = *(const float4*)&b2[d];
    float4 x1 = *(const float4*)&X1[idx];
    float4 t1 = *(const float4*)&T1[b * D_ + d];
    float4 t2 = *(const float4*)&T2[b * D_ + d];
    o.x += x1.x * t1.x + t2.x; o.y += x1.y * t1.y + t2.y;
    o.z += x1.z * t1.z + t2.z; o.w += x1.w * t1.w + t2.w;
#pragma unroll
    for (int s = 0; s < FS; ++s) {
        float4 p = *(const float4*)&Pf[(size_t)s * (B_ * N_ * D_) + idx];
        o.x += p.x; o.y += p.y; o.z += p.z; o.w += p.w;
    }
    *(float4*)&X2[idx] = o;
}

// ---------------- fused instance-norm stats + apply -> out ----------------
__global__ __launch_bounds__(256) void stats_apply_kernel(const float* __restrict__ X,
    const float* __restrict__ gamma, const float* __restrict__ beta,
    float* __restrict__ Y)
{
    const int b  = blockIdx.x >> 3;
    const int dg = blockIdx.x & 7;
    const int dl = threadIdx.x & 15;
    const int nc = threadIdx.x >> 4;
    const int d  = dg * 16 + dl;
    const float* xb = X + (size_t)b * N_ * D_ + d;
    float s = 0.f, q = 0.f;
#pragma unroll 4
    for (int i = 0; i < 32; ++i) {
        float x = xb[(size_t)(nc * 32 + i) * D_];
        s += x; q += x * x;
    }
    __shared__ float ls[16][17], lq[16][17];
    __shared__ float t1l[16], t2l[16];
    ls[nc][dl] = s; lq[nc][dl] = q;
    __syncthreads();
    if (threadIdx.x < 16) {
        float S = 0.f, Q2 = 0.f;
#pragma unroll
        for (int i = 0; i < 16; ++i) { S += ls[i][threadIdx.x]; Q2 += lq[i][threadIdx.x]; }
        int dd = dg * 16 + threadIdx.x;
        float mean = S * (1.0f / N_);
        float var  = Q2 * (1.0f / N_) - mean * mean;
        float r = 1.0f / sqrtf(var + 1e-5f);
        float t1 = r * gamma[dd];
        t1l[threadIdx.x] = t1;
        t2l[threadIdx.x] = beta[dd] - mean * t1;
    }
    __syncthreads();
    const float t1 = t1l[dl], t2 = t2l[dl];
    float* yb = Y + (size_t)b * N_ * D_ + d;
#pragma unroll 4
    for (int i = 0; i < 32; ++i) {
        size_t off = (size_t)(nc * 32 + i) * D_;
        yb[off] = xb[off] * t1 + t2;
    }
}

extern "C" void kernel_launch(void* const* d_in, const int* in_sizes, int n_in,
                              void* d_out, int out_size, void* d_ws, size_t ws_size,
                              hipStream_t stream)
{
    const float* h      = (const float*)d_in[0];
    const float* coords = (const float*)d_in[1];
    const float* W_Q    = (const float*)d_in[2];
    const float* W_K    = (const float*)d_in[3];
    const float* W_V    = (const float*)d_in[4];
    const float* W_O    = (const float*)d_in[5];
    const float* emb    = (const float*)d_in[6];
    const float* w1     = (const float*)d_in[7];
    const float* b1     = (const float*)d_in[8];
    const float* w2     = (const float*)d_in[9];
    const float* b2     = (const float*)d_in[10];
    const float* g1     = (const float*)d_in[11];
    const float* be1    = (const float*)d_in[12];
    const float* g2     = (const float*)d_in[13];
    const float* be2    = (const float*)d_in[14];
    float* out = (float*)d_out;

    float* ws = (float*)d_ws;
    const size_t R = (size_t)B_ * N_;          // 2048 rows
    float* Qb  = ws;
    float* Kb  = Qb + R * D_;
    float* Vb  = Kb + R * D_;
    float* QEb = Vb + R * D_;                  // R*H*NB
    float* X1  = QEb + R * H_ * NB;
    float* F1  = X1 + R * D_;                  // R * DFF
    float* X2  = F1 + R * DFF;
    float* Pb  = X2 + R * D_;                  // 2048 * 64 * 17
    float* Pf  = Pb + (size_t)2048 * 64 * 17;  // FS * R * D
    float* T1a = Pf + (size_t)FS * R * D_;
    float* T2a = T1a + B_ * D_;

    // 1. Q,K,V projections + QE table (fused into z=0)
    qkv_qe_kernel<<<dim3(128, 1, 3), 256, 0, stream>>>(
        h, W_Q, W_K, W_V, emb, Qb, Kb, Vb, QEb);
    // 2. attention (KS=8 -> 2048 blocks) -> partials
    attn5_kernel<<<dim3(2048), 256, 0, stream>>>(Qb, Kb, Vb, QEb, coords, Pb);
    // 3. O-projection (combine prologue + residual h)
    oproj_kernel<<<dim3((int)R / 16), 256, 0, stream>>>(Pb, W_O, h, X1);
    // 4. instance-norm-1 stats -> affine tables
    stats_kernel<<<dim3(B_ * 8), 256, 0, stream>>>(X1, g1, be1, T1a, T2a);
    // 5. FFN1 (norm prologue; relu; ROWS=8, 4 col-slices)
    ffn1_kernel<<<dim3(64, 4), 256, 0, stream>>>(X1, T1a, T2a, w1, b1, F1);
    // 6. FFN2 split-K partials (FS=8 -> 512 blocks)
    ffn2s_kernel<<<dim3(64, 1, FS), 256, 0, stream>>>(F1, w2, Pf);
    // 7. FFN2 combine (+bias, + inline norm1(X1) residual)
    fcomb_kernel<<<dim3((int)(R * D_) / 1024), 256, 0, stream>>>(Pf, b2, X1, T1a, T2a, X2);
    // 8. instance-norm-2 stats + apply -> out
    stats_apply_kernel<<<dim3(B_ * 8), 256, 0, stream>>>(X2, g2, be2, out);
}

// Round 8
// 84.564 us; speedup vs baseline: 1.3946x; 1.0243x over previous
//
#include <hip/hip_runtime.h>
#include <hip/hip_bf16.h>

#define B_  4
#define N_  512
#define D_  128
#define H_  8
#define DK  16
#define DFF 512
#define NB  32
#define KS  8            // key-split factor for attention
#define FS  8            // ffn2 K-split factor

// ---------------- QKV projections + fused QE table ----------------
// Wave = 2 rows x 128 cols (2/lane); block = 8 rows; grid (256,1,3) = 768 blocks.
// z==0 blocks also compute QE[row,h,k] = Q[row,h,:].emb[k,h,:] from LDS-staged Q.
__global__ __launch_bounds__(256) void qkv_qe_kernel(
    const float* __restrict__ A,
    const float* __restrict__ WQ, const float* __restrict__ WK, const float* __restrict__ WV,
    const float* __restrict__ emb,
    float* __restrict__ Qo, float* __restrict__ Ko, float* __restrict__ Vo,
    float* __restrict__ QE)
{
    const float* Bw = blockIdx.z == 0 ? WQ : (blockIdx.z == 1 ? WK : WV);
    float*       C  = blockIdx.z == 0 ? Qo : (blockIdx.z == 1 ? Ko : Vo);
    const int wave = threadIdx.x >> 6;
    const int lane = threadIdx.x & 63;
    const int rbase = __builtin_amdgcn_readfirstlane((blockIdx.x * 4 + wave) * 2);
    const int col = lane * 2;

    float acc[2][2] = {};
#pragma unroll 2
    for (int k0 = 0; k0 < D_; k0 += 4) {
        float4 a0 = *(const float4*)&A[(size_t)(rbase + 0) * D_ + k0];
        float4 a1 = *(const float4*)&A[(size_t)(rbase + 1) * D_ + k0];
#pragma unroll
        for (int kk = 0; kk < 4; ++kk) {
            float2 bv = *(const float2*)&Bw[(size_t)(k0 + kk) * D_ + col];
            float x0 = (&a0.x)[kk], x1 = (&a1.x)[kk];
            acc[0][0] += x0 * bv.x; acc[0][1] += x0 * bv.y;
            acc[1][0] += x1 * bv.x; acc[1][1] += x1 * bv.y;
        }
    }
    *(float2*)&C[(size_t)(rbase + 0) * D_ + col] = make_float2(acc[0][0], acc[0][1]);
    *(float2*)&C[(size_t)(rbase + 1) * D_ + col] = make_float2(acc[1][0], acc[1][1]);

    if (blockIdx.z == 0) {
        __shared__ float Qls[8][132];
        *(float2*)&Qls[wave * 2 + 0][col] = make_float2(acc[0][0], acc[0][1]);
        *(float2*)&Qls[wave * 2 + 1][col] = make_float2(acc[1][0], acc[1][1]);
        __syncthreads();
        // thread -> (row r of 8, head h of 8, k-quarter of 4), 8 buckets each
        const int r  = threadIdx.x >> 5;
        const int hh = (threadIdx.x >> 2) & 7;
        const int k0 = (threadIdx.x & 3) * 8;
        const int grow = blockIdx.x * 8 + r;
        const float4* qv = (const float4*)&Qls[r][hh * DK];
        const float4 qa = qv[0], qb = qv[1], qc = qv[2], qd = qv[3];
        float* qe_out = QE + ((size_t)grow * H_ + hh) * NB + k0;
#pragma unroll 2
        for (int k = 0; k < 8; ++k) {
            const float4* ep = (const float4*)(emb + (size_t)(k0 + k) * D_ + hh * DK);
            float4 e0 = ep[0], e1 = ep[1], e2 = ep[2], e3 = ep[3];
            float dot = qa.x*e0.x + qa.y*e0.y + qa.z*e0.z + qa.w*e0.w
                      + qb.x*e1.x + qb.y*e1.y + qb.z*e1.z + qb.w*e1.w
                      + qc.x*e2.x + qc.y*e2.y + qc.z*e2.z + qc.w*e2.w
                      + qd.x*e3.x + qd.y*e3.y + qd.z*e3.z + qd.w*e3.w;
            qe_out[k] = dot;
        }
    }
}

// ---------------- attention v6: LDS-staged K/V tiles, KS=8 key-split ----------------
// grid = 2048 blocks; LDS ~35KB -> 4 blocks/CU, 16 waves/CU. Inner loop reads K/V
// from LDS (wave-uniform broadcast, ~12cyc) instead of L2 (~200cyc) -> VALU-bound.
__global__ __launch_bounds__(256) void attn6_kernel(
    const float* __restrict__ Q, const float* __restrict__ K, const float* __restrict__ V,
    const float* __restrict__ QE, const float* __restrict__ coords,
    float* __restrict__ P)
{
    const int tid  = threadIdx.x;
    const int wave = tid >> 6;
    const int lane = tid & 63;
    const int bid  = blockIdx.x;
    const int ks    = bid & 7;
    const int chunk = (bid >> 3) & 7;
    const int h     = (bid >> 6) & (H_ - 1);
    const int b     = bid >> 9;

    const int n   = chunk * 64 + lane;
    const int row = b * N_ + n;

    __shared__ float kl[64][16];               // staged K tile (64 keys x 16)
    __shared__ float vl[64][16];               // staged V tile
    __shared__ float qel[64][NB + 1];          // per-row QE table
    __shared__ float ckrd[64][2];              // key coords
    __shared__ float accl[4][64][17];          // per-wave partials

    const size_t hdbase = (size_t)b * N_ * D_ + h * DK;

    {   // stage K/V: thread t -> key t>>2, 16B part t&3 (coalesced 64B per 4 thr)
        int key = tid >> 2, part = tid & 3;
        size_t g = hdbase + (size_t)(ks * 64 + key) * D_ + part * 4;
        *(float4*)&kl[key][part * 4] = *(const float4*)&K[g];
        *(float4*)&vl[key][part * 4] = *(const float4*)&V[g];
    }
    {   // stage QE table: 64 rows x 32 buckets
        int r = tid >> 2, part = tid & 3;
        const float* src = QE + ((size_t)(b * N_ + chunk * 64 + r) * H_ + h) * NB + part * 8;
#pragma unroll
        for (int j = 0; j < 8; ++j) qel[r][part * 8 + j] = src[j];
    }
    if (tid < 128)
        ((float*)ckrd)[tid] = coords[(size_t)(b * N_ + ks * 64) * 2 + tid];

    const float4* qp = (const float4*)(Q + (size_t)row * D_ + h * DK);
    const float4 q0 = qp[0], q1 = qp[1], q2 = qp[2], q3 = qp[3];
    const float cx = coords[(size_t)row * 2 + 0];
    const float cy = coords[(size_t)row * 2 + 1];

    __syncthreads();

    float l = 0.f;
    float acc[16] = {};

    const int ml0 = wave * 16;
#pragma unroll 4
    for (int i = 0; i < 16; ++i) {
        const int ml = ml0 + i;
        const float4* kp = (const float4*)&kl[ml][0];
        const float4 k0 = kp[0], k1 = kp[1], k2 = kp[2], k3 = kp[3];
        float dot = q0.x*k0.x + q0.y*k0.y + q0.z*k0.z + q0.w*k0.w
                  + q1.x*k1.x + q1.y*k1.y + q1.z*k1.z + q1.w*k1.w
                  + q2.x*k2.x + q2.y*k2.y + q2.z*k2.z + q2.w*k2.w
                  + q3.x*k3.x + q3.y*k3.y + q3.z*k3.z + q3.w*k3.w;
        float dx = cx - ckrd[ml][0], dy = cy - ckrd[ml][1];
        float dist = sqrtf(dx * dx + dy * dy);
        int bucket = (int)(dist * 32.0f);
        bucket = bucket > (NB - 1) ? (NB - 1) : bucket;
        float s = dot * 0.25f + qel[lane][bucket];
        float p = __expf(s);
        l += p;
        const float4* vp = (const float4*)&vl[ml][0];
        const float4 v0 = vp[0], v1 = vp[1], v2 = vp[2], v3 = vp[3];
        acc[0]  += p * v0.x; acc[1]  += p * v0.y; acc[2]  += p * v0.z; acc[3]  += p * v0.w;
        acc[4]  += p * v1.x; acc[5]  += p * v1.y; acc[6]  += p * v1.z; acc[7]  += p * v1.w;
        acc[8]  += p * v2.x; acc[9]  += p * v2.y; acc[10] += p * v2.z; acc[11] += p * v2.w;
        acc[12] += p * v3.x; acc[13] += p * v3.y; acc[14] += p * v3.z; acc[15] += p * v3.w;
    }

    accl[wave][lane][16] = l;
#pragma unroll
    for (int j = 0; j < 16; ++j) accl[wave][lane][j] = acc[j];
    __syncthreads();

    float* pb = P + (size_t)bid * (64 * 17);
    for (int i = tid; i < 64 * 17; i += 256) {
        int r = i / 17, j = i - r * 17;
        pb[i] = accl[0][r][j] + accl[1][r][j] + accl[2][r][j] + accl[3][r][j];
    }
}

// ---------------- O-proj: combine KS partials in LDS + ROWS=2 GEMV + h residual ------
// grid = 256 blocks (8 rows each) -> 1/CU x 4 waves; combine is load-heavy, GEMV short.
__global__ __launch_bounds__(256) void oproj_kernel(
    const float* __restrict__ P, const float* __restrict__ WO,
    const float* __restrict__ hres, float* __restrict__ X1)
{
    const int tid = threadIdx.x;
    const int gr0 = blockIdx.x * 8;
    __shared__ float AOls[8][128];
    __shared__ float lsl[8][8];

    // denominators: 64 (row, head) pairs
    if (tid < 64) {
        int r = tid >> 3, hh = tid & 7;
        int gr = gr0 + r;
        int b = gr >> 9, n = gr & (N_ - 1);
        int chunk = n >> 6, rl = n & 63;
        size_t base = ((size_t)(((b * H_ + hh) * 8 + chunk) * KS)) * (64 * 17) + (size_t)rl * 17;
        float l = 0.f;
#pragma unroll
        for (int s = 0; s < KS; ++s) l += P[base + (size_t)s * (64 * 17) + 16];
        lsl[r][hh] = l;
    }

    // numerators: 8 rows x 128 d = 1024, 4 per thread
    float asum[4];
#pragma unroll
    for (int j = 0; j < 4; ++j) {
        int i = tid + j * 256;
        int r = i >> 7, d = i & 127;
        int gr = gr0 + r;
        int b = gr >> 9, n = gr & (N_ - 1);
        int chunk = n >> 6, rl = n & 63;
        int hh = d >> 4, dk = d & 15;
        size_t base = ((size_t)(((b * H_ + hh) * 8 + chunk) * KS)) * (64 * 17) + (size_t)rl * 17 + dk;
        float a = 0.f;
#pragma unroll
        for (int s = 0; s < KS; ++s) a += P[base + (size_t)s * (64 * 17)];
        asum[j] = a;
    }
    __syncthreads();
#pragma unroll
    for (int j = 0; j < 4; ++j) {
        int i = tid + j * 256;
        int r = i >> 7, d = i & 127;
        AOls[r][d] = asum[j] / lsl[r][d >> 4];
    }
    __syncthreads();

    const int wave = tid >> 6;
    const int lane = tid & 63;
    const int rl = wave * 2;
    const int grb = __builtin_amdgcn_readfirstlane(gr0 + rl);
    const int col = lane * 2;

    float acc[2][2] = {};
#pragma unroll 2
    for (int k0 = 0; k0 < D_; k0 += 4) {
        float4 a0 = *(const float4*)&AOls[rl + 0][k0];
        float4 a1 = *(const float4*)&AOls[rl + 1][k0];
#pragma unroll
        for (int kk = 0; kk < 4; ++kk) {
            float2 bv = *(const float2*)&WO[(size_t)(k0 + kk) * D_ + col];
            float x0 = (&a0.x)[kk], x1 = (&a1.x)[kk];
            acc[0][0] += x0 * bv.x; acc[0][1] += x0 * bv.y;
            acc[1][0] += x1 * bv.x; acc[1][1] += x1 * bv.y;
        }
    }
#pragma unroll
    for (int j = 0; j < 2; ++j) {
        float2 rv = *(const float2*)&hres[(size_t)(grb + j) * D_ + col];
        *(float2*)&X1[(size_t)(grb + j) * D_ + col] =
            make_float2(acc[j][0] + rv.x, acc[j][1] + rv.y);
    }
}

// ---------------- instance-norm stats (128 blocks): T1 = r*g, T2 = be - m*r*g --------
__global__ __launch_bounds__(256) void stats_kernel(const float* __restrict__ X,
    const float* __restrict__ gamma, const float* __restrict__ beta,
    float* __restrict__ T1, float* __restrict__ T2)
{
    const int b  = blockIdx.x >> 5;
    const int dg = blockIdx.x & 31;            // group of 4 d's
    const int dl = threadIdx.x & 3;
    const int nc = threadIdx.x >> 2;           // 64 chunks of 8 n
    const float* xp = X + ((size_t)b * N_ + nc * 8) * D_ + dg * 4 + dl;
    float s = 0.f, q = 0.f;
#pragma unroll
    for (int i = 0; i < 8; ++i) { float x = xp[(size_t)i * D_]; s += x; q += x * x; }
    __shared__ float rs[64][4], rq[64][4];
    rs[nc][dl] = s; rq[nc][dl] = q;
    __syncthreads();
    for (int off = 32; off >= 1; off >>= 1) {
        if (nc < off) { rs[nc][dl] += rs[nc + off][dl]; rq[nc][dl] += rq[nc + off][dl]; }
        __syncthreads();
    }
    if (threadIdx.x < 4) {
        int d = dg * 4 + threadIdx.x;
        float mean = rs[0][threadIdx.x] * (1.0f / N_);
        float var  = rq[0][threadIdx.x] * (1.0f / N_) - mean * mean;
        float r = 1.0f / sqrtf(var + 1e-5f);
        float t1 = r * gamma[d];
        T1[b * D_ + d] = t1;
        T2[b * D_ + d] = beta[d] - mean * t1;
    }
}

// ---------------- FFN1: norm(X1) prologue in LDS; wave = 4 rows x 128-col slice ------
// grid (128, 4) = 512 blocks (2/CU).
__global__ __launch_bounds__(256) void ffn1_kernel(
    const float* __restrict__ X1, const float* __restrict__ T1, const float* __restrict__ T2,
    const float* __restrict__ w1, const float* __restrict__ b1, float* __restrict__ F1)
{
    __shared__ float Als[16][128];
    const int gr0 = blockIdx.x * 16;
    const int b = gr0 >> 9;
#pragma unroll
    for (int i = threadIdx.x * 4; i < 16 * 128; i += 1024) {
        int r = i >> 7, c = i & 127;
        float4 x  = *(const float4*)&X1[(size_t)(gr0 + r) * D_ + c];
        float4 t1 = *(const float4*)&T1[b * D_ + c];
        float4 t2 = *(const float4*)&T2[b * D_ + c];
        float4 y;
        y.x = x.x * t1.x + t2.x; y.y = x.y * t1.y + t2.y;
        y.z = x.z * t1.z + t2.z; y.w = x.w * t1.w + t2.w;
        *(float4*)&Als[r][c] = y;
    }
    __syncthreads();

    const int wave = threadIdx.x >> 6;
    const int lane = threadIdx.x & 63;
    const int rl = wave * 4;
    const int grb = __builtin_amdgcn_readfirstlane(gr0 + rl);
    const int col = blockIdx.y * 128 + lane * 2;

    float acc[4][2] = {};
#pragma unroll 2
    for (int k0 = 0; k0 < D_; k0 += 4) {
        float4 a4[4];
#pragma unroll
        for (int j = 0; j < 4; ++j) a4[j] = *(const float4*)&Als[rl + j][k0];
#pragma unroll
        for (int kk = 0; kk < 4; ++kk) {
            float2 bv = *(const float2*)&w1[(size_t)(k0 + kk) * DFF + col];
#pragma unroll
            for (int j = 0; j < 4; ++j) {
                float a = (&a4[j].x)[kk];
                acc[j][0] += a * bv.x;
                acc[j][1] += a * bv.y;
            }
        }
    }
    float2 bb = *(const float2*)&b1[col];
#pragma unroll
    for (int j = 0; j < 4; ++j) {
        float o0 = fmaxf(acc[j][0] + bb.x, 0.f);
        float o1 = fmaxf(acc[j][1] + bb.y, 0.f);
        *(float2*)&F1[(size_t)(grb + j) * DFF + col] = make_float2(o0, o1);
    }
}

// ---------------- FFN2 split-K (FS=8): wave = 4 rows; grid (128,1,8) = 1024 blocks ----
__global__ __launch_bounds__(256) void ffn2s_kernel(
    const float* __restrict__ F1, const float* __restrict__ w2, float* __restrict__ Pf)
{
    const int wave = threadIdx.x >> 6;
    const int lane = threadIdx.x & 63;
    const int rbase = __builtin_amdgcn_readfirstlane((blockIdx.x * 4 + wave) * 4);
    const int col = lane * 2;
    const int s = blockIdx.z;
    const int kbeg = s * (DFF / FS);

    float acc[4][2] = {};
#pragma unroll 2
    for (int k0 = kbeg; k0 < kbeg + DFF / FS; k0 += 4) {
        float4 a4[4];
#pragma unroll
        for (int j = 0; j < 4; ++j)
            a4[j] = *(const float4*)&F1[(size_t)(rbase + j) * DFF + k0];
#pragma unroll
        for (int kk = 0; kk < 4; ++kk) {
            float2 bv = *(const float2*)&w2[(size_t)(k0 + kk) * D_ + col];
#pragma unroll
            for (int j = 0; j < 4; ++j) {
                float a = (&a4[j].x)[kk];
                acc[j][0] += a * bv.x;
                acc[j][1] += a * bv.y;
            }
        }
    }
#pragma unroll
    for (int j = 0; j < 4; ++j)
        *(float2*)&Pf[((size_t)s * (B_ * N_) + rbase + j) * D_ + col] =
            make_float2(acc[j][0], acc[j][1]);
}

// ---------------- FFN2 combine: X2 = sum_s Pf[s] + b2 + (X1*T1+T2) residual ----------
__global__ __launch_bounds__(256) void fcomb_kernel(
    const float* __restrict__ Pf, const float* __restrict__ b2,
    const float* __restrict__ X1, const float* __restrict__ T1, const float* __restrict__ T2,
    float* __restrict__ X2)
{
    int idx = (blockIdx.x * 256 + threadIdx.x) * 4;
    int d = idx & (D_ - 1);
    int b = idx >> 16;
    float4 o  = *(const float4*)&b2[d];
    float4 x1 = *(const float4*)&X1[idx];
    float4 t1 = *(const float4*)&T1[b * D_ + d];
    float4 t2 = *(const float4*)&T2[b * D_ + d];
    o.x += x1.x * t1.x + t2.x; o.y += x1.y * t1.y + t2.y;
    o.z += x1.z * t1.z + t2.z; o.w += x1.w * t1.w + t2.w;
#pragma unroll
    for (int s = 0; s < FS; ++s) {
        float4 p = *(const float4*)&Pf[(size_t)s * (B_ * N_ * D_) + idx];
        o.x += p.x; o.y += p.y; o.z += p.z; o.w += p.w;
    }
    *(float4*)&X2[idx] = o;
}

// ---------------- fused instance-norm stats + apply -> out (128 blocks) --------------
__global__ __launch_bounds__(256) void stats_apply_kernel(const float* __restrict__ X,
    const float* __restrict__ gamma, const float* __restrict__ beta,
    float* __restrict__ Y)
{
    const int b  = blockIdx.x >> 5;
    const int dg = blockIdx.x & 31;
    const int dl = threadIdx.x & 3;
    const int nc = threadIdx.x >> 2;
    const float* xp = X + ((size_t)b * N_ + nc * 8) * D_ + dg * 4 + dl;
    float s = 0.f, q = 0.f;
#pragma unroll
    for (int i = 0; i < 8; ++i) { float x = xp[(size_t)i * D_]; s += x; q += x * x; }
    __shared__ float rs[64][4], rq[64][4];
    __shared__ float t1l[4], t2l[4];
    rs[nc][dl] = s; rq[nc][dl] = q;
    __syncthreads();
    for (int off = 32; off >= 1; off >>= 1) {
        if (nc < off) { rs[nc][dl] += rs[nc + off][dl]; rq[nc][dl] += rq[nc + off][dl]; }
        __syncthreads();
    }
    if (threadIdx.x < 4) {
        int d = dg * 4 + threadIdx.x;
        float mean = rs[0][threadIdx.x] * (1.0f / N_);
        float var  = rq[0][threadIdx.x] * (1.0f / N_) - mean * mean;
        float r = 1.0f / sqrtf(var + 1e-5f);
        float t1 = r * gamma[d];
        t1l[threadIdx.x] = t1;
        t2l[threadIdx.x] = beta[d] - mean * t1;
    }
    __syncthreads();
    const float t1 = t1l[dl], t2 = t2l[dl];
    float* yp = Y + ((size_t)b * N_ + nc * 8) * D_ + dg * 4 + dl;
#pragma unroll
    for (int i = 0; i < 8; ++i) yp[(size_t)i * D_] = xp[(size_t)i * D_] * t1 + t2;
}

extern "C" void kernel_launch(void* const* d_in, const int* in_sizes, int n_in,
                              void* d_out, int out_size, void* d_ws, size_t ws_size,
                              hipStream_t stream)
{
    const float* h      = (const float*)d_in[0];
    const float* coords = (const float*)d_in[1];
    const float* W_Q    = (const float*)d_in[2];
    const float* W_K    = (const float*)d_in[3];
    const float* W_V    = (const float*)d_in[4];
    const float* W_O    = (const float*)d_in[5];
    const float* emb    = (const float*)d_in[6];
    const float* w1     = (const float*)d_in[7];
    const float* b1     = (const float*)d_in[8];
    const float* w2     = (const float*)d_in[9];
    const float* b2     = (const float*)d_in[10];
    const float* g1     = (const float*)d_in[11];
    const float* be1    = (const float*)d_in[12];
    const float* g2     = (const float*)d_in[13];
    const float* be2    = (const float*)d_in[14];
    float* out = (float*)d_out;

    float* ws = (float*)d_ws;
    const size_t R = (size_t)B_ * N_;          // 2048 rows
    float* Qb  = ws;
    float* Kb  = Qb + R * D_;
    float* Vb  = Kb + R * D_;
    float* QEb = Vb + R * D_;                  // R*H*NB
    float* X1  = QEb + R * H_ * NB;
    float* F1  = X1 + R * D_;                  // R * DFF
    float* X2  = F1 + R * DFF;
    float* Pb  = X2 + R * D_;                  // 2048 * 64 * 17
    float* Pf  = Pb + (size_t)2048 * 64 * 17;  // FS * R * D
    float* T1a = Pf + (size_t)FS * R * D_;
    float* T2a = T1a + B_ * D_;

    // 1. Q,K,V projections + QE table (768 blocks)
    qkv_qe_kernel<<<dim3(256, 1, 3), 256, 0, stream>>>(
        h, W_Q, W_K, W_V, emb, Qb, Kb, Vb, QEb);
    // 2. attention (LDS-staged K/V; 2048 blocks) -> partials
    attn6_kernel<<<dim3(2048), 256, 0, stream>>>(Qb, Kb, Vb, QEb, coords, Pb);
    // 3. O-projection (combine prologue + residual h; 256 blocks)
    oproj_kernel<<<dim3((int)R / 8), 256, 0, stream>>>(Pb, W_O, h, X1);
    // 4. instance-norm-1 stats (128 blocks)
    stats_kernel<<<dim3(B_ * 32), 256, 0, stream>>>(X1, g1, be1, T1a, T2a);
    // 5. FFN1 (norm prologue; relu; 512 blocks)
    ffn1_kernel<<<dim3(128, 4), 256, 0, stream>>>(X1, T1a, T2a, w1, b1, F1);
    // 6. FFN2 split-K partials (1024 blocks)
    ffn2s_kernel<<<dim3(128, 1, FS), 256, 0, stream>>>(F1, w2, Pf);
    // 7. FFN2 combine (+bias, + inline norm1(X1) residual; 256 blocks)
    fcomb_kernel<<<dim3((int)(R * D_) / 1024), 256, 0, stream>>>(Pf, b2, X1, T1a, T2a, X2);
    // 8. instance-norm-2 stats + apply -> out (128 blocks)
    stats_apply_kernel<<<dim3(B_ * 32), 256, 0, stream>>>(X2, g2, be2, out);
}